// Round 3
// baseline (160.922 us; speedup 1.0000x reference)
//
#include <hip/hip_runtime.h>
#include <hip/hip_bf16.h>

typedef __attribute__((ext_vector_type(8))) __bf16 bf16x8;
typedef __attribute__((ext_vector_type(4))) float f32x4;

#define N_NODES 50000
#define N_EDGES 800000
#define N_TILES (N_EDGES / 16)   // 50000 16-edge tiles
#define WAVES 4
#define TPW 8                    // tiles per wave per block
#define TILES_PER_BLOCK (WAVES * TPW)   // 32 -> 512 edges/block

__global__ __launch_bounds__(256, 2) void edge_mlp_kernel(
    const float* __restrict__ x_s, const float* __restrict__ x_t,
    const int* __restrict__ edge_index, const float* __restrict__ edge_attr,
    const float* __restrict__ u, const int* __restrict__ batch_e,
    const float* __restrict__ W1, const float* __restrict__ b1,
    const float* __restrict__ W2, const float* __restrict__ b2,
    float* __restrict__ out)
{
    __shared__ __align__(16) __bf16 sW1t[64][264];      // [n][k] 33792 B
    __shared__ __align__(16) __bf16 sW2t[64][72];       // [n][k]  9216 B
    __shared__ __align__(16) __bf16 sH1[WAVES][16][72]; //         9216 B
    __shared__ float sB1[64];
    __shared__ float sB2[64];

    const int t = threadIdx.x;

    for (int idx = t; idx < 256 * 64; idx += 256) {
        int k = idx >> 6, n = idx & 63;
        sW1t[n][k] = (__bf16)W1[idx];
    }
    for (int idx = t; idx < 64 * 64; idx += 256) {
        int k = idx >> 6, n = idx & 63;
        sW2t[n][k] = (__bf16)W2[idx];
    }
    if (t < 64) { sB1[t] = b1[t]; sB2[t] = b2[t]; }
    __syncthreads();

    const int wave = t >> 6;
    const int lane = t & 63;
    const int l15  = lane & 15;   // A row / B col within 16
    const int lk   = lane >> 4;   // k-group 0..3

    const int tile_base = (blockIdx.x * WAVES + wave) * TPW;

    // ---- preload ALL indices for this wave's 8 tiles (hides idx latency) ----
    int srcs[TPW], tgts[TPW], bgs[TPW];
    #pragma unroll
    for (int i = 0; i < TPW; ++i) {
        const int tile = tile_base + i;
        if (tile < N_TILES) {
            const int e = tile * 16 + l15;
            srcs[i] = edge_index[e];
            tgts[i] = edge_index[N_EDGES + e];
            bgs[i]  = batch_e[e];
        } else { srcs[i] = 0; tgts[i] = 0; bgs[i] = 0; }
    }

    #pragma unroll
    for (int i = 0; i < TPW; ++i) {
        const int tile = tile_base + i;
        if (tile >= N_TILES) break;
        const int e = tile * 16 + l15;

        const float* seg0 = x_s + (long long)srcs[i] * 64;
        const float* seg1 = x_t + (long long)tgts[i] * 64;
        const float* seg2 = edge_attr + (long long)e * 64;
        const float* seg3 = u + (long long)bgs[i] * 64;

        // ---- issue ALL 16 loads (64 VGPR in flight, one latency wave) ----
        float4 f[16];
        #pragma unroll
        for (int c = 0; c < 8; ++c) {
            const float* s = (c < 2) ? seg0 : (c < 4) ? seg1 : (c < 6) ? seg2 : seg3;
            const float* p = s + ((c & 1) * 32 + lk * 8);
            f[2 * c]     = *(const float4*)p;
            f[2 * c + 1] = *(const float4*)(p + 4);
        }

        // ---- convert to bf16 A-fragments ----
        bf16x8 a[8];
        #pragma unroll
        for (int c = 0; c < 8; ++c) {
            a[c][0] = (__bf16)f[2*c].x;   a[c][1] = (__bf16)f[2*c].y;
            a[c][2] = (__bf16)f[2*c].z;   a[c][3] = (__bf16)f[2*c].w;
            a[c][4] = (__bf16)f[2*c+1].x; a[c][5] = (__bf16)f[2*c+1].y;
            a[c][6] = (__bf16)f[2*c+1].z; a[c][7] = (__bf16)f[2*c+1].w;
        }

        // ---- GEMM1: [16 x 256] x [256 x 64] ----
        f32x4 acc[4] = {{0,0,0,0},{0,0,0,0},{0,0,0,0},{0,0,0,0}};
        #pragma unroll
        for (int kk = 0; kk < 8; ++kk) {
            const int k0 = kk * 32 + lk * 8;
            #pragma unroll
            for (int nf = 0; nf < 4; ++nf) {
                bf16x8 b = *(const bf16x8*)&sW1t[nf * 16 + l15][k0];
                acc[nf] = __builtin_amdgcn_mfma_f32_16x16x32_bf16(a[kk], b, acc[nf], 0, 0, 0);
            }
        }

        // ---- bias + LeakyReLU(0.1) -> bf16 -> per-wave LDS tile ----
        #pragma unroll
        for (int nf = 0; nf < 4; ++nf) {
            const float bv = sB1[nf * 16 + l15];
            #pragma unroll
            for (int r = 0; r < 4; ++r) {
                float v = acc[nf][r] + bv;
                v = (v >= 0.f) ? v : 0.1f * v;
                sH1[wave][lk * 4 + r][nf * 16 + l15] = (__bf16)v;  // C: row=lk*4+r, col=l15
            }
        }
        // per-wave LDS RAW: compiler inserts the lgkmcnt wait

        // ---- GEMM2: [16 x 64] x [64 x 64] ----
        f32x4 acc2[4] = {{0,0,0,0},{0,0,0,0},{0,0,0,0},{0,0,0,0}};
        #pragma unroll
        for (int kk = 0; kk < 2; ++kk) {
            const int k0 = kk * 32 + lk * 8;
            bf16x8 a2 = *(const bf16x8*)&sH1[wave][l15][k0];
            #pragma unroll
            for (int nf = 0; nf < 4; ++nf) {
                bf16x8 b = *(const bf16x8*)&sW2t[nf * 16 + l15][k0];
                acc2[nf] = __builtin_amdgcn_mfma_f32_16x16x32_bf16(a2, b, acc2[nf], 0, 0, 0);
            }
        }

        // ---- + b2, store fp32 ----
        float* orow = out + (long long)tile * 16 * 64;
        #pragma unroll
        for (int nf = 0; nf < 4; ++nf) {
            const float bv = sB2[nf * 16 + l15];
            #pragma unroll
            for (int r = 0; r < 4; ++r) {
                orow[(lk * 4 + r) * 64 + nf * 16 + l15] = acc2[nf][r] + bv;
            }
        }
    }
}

extern "C" void kernel_launch(void* const* d_in, const int* in_sizes, int n_in,
                              void* d_out, int out_size, void* d_ws, size_t ws_size,
                              hipStream_t stream) {
    const float* x_s       = (const float*)d_in[0];
    const float* x_t       = (const float*)d_in[1];
    const int*   edge_index= (const int*)d_in[2];   // harness: integer -> int32
    const float* edge_attr = (const float*)d_in[3];
    const float* u         = (const float*)d_in[4];
    const int*   batch_e   = (const int*)d_in[5];
    const float* W1        = (const float*)d_in[6];
    const float* b1        = (const float*)d_in[7];
    const float* W2        = (const float*)d_in[8];
    const float* b2        = (const float*)d_in[9];
    float*       out       = (float*)d_out;

    const int nblocks = (N_TILES + TILES_PER_BLOCK - 1) / TILES_PER_BLOCK; // 1563
    edge_mlp_kernel<<<nblocks, 256, 0, stream>>>(
        x_s, x_t, edge_index, edge_attr, u, batch_e, W1, b1, W2, b2, out);
}